// Round 5
// baseline (429.501 us; speedup 1.0000x reference)
//
#include <hip/hip_runtime.h>
#include <stdint.h>

typedef unsigned short u16;
typedef __attribute__((ext_vector_type(8))) short short8;
typedef __attribute__((ext_vector_type(4))) short s16x4;
typedef __attribute__((ext_vector_type(4))) float f32x4;

__device__ __forceinline__ u16 f2bf(float f) {
  uint32_t x = __float_as_uint(f);
  x += 0x7fff + ((x >> 16) & 1);
  return (u16)(x >> 16);
}
__device__ __forceinline__ float bf2f(u16 u) {
  return __uint_as_float(((uint32_t)u) << 16);
}
__device__ __forceinline__ f32x4 mfma16(short8 a, short8 b, f32x4 c) {
  return __builtin_amdgcn_mfma_f32_16x16x32_bf16(a, b, c, 0, 0, 0);
}
__device__ __forceinline__ f32x4 mfma16k16(s16x4 a, s16x4 b, f32x4 c) {
  return __builtin_amdgcn_mfma_f32_16x16x16bf16_1k(a, b, c, 0, 0, 0);
}
__device__ __forceinline__ void gld16(const u16* g, u16* l) {
  __builtin_amdgcn_global_load_lds(
      (const __attribute__((address_space(1))) unsigned int*)g,
      (__attribute__((address_space(3))) unsigned int*)l, 16, 0, 0);
}
__device__ __forceinline__ float exp2a(float x) {  // raw v_exp_f32 (2^x)
  float r;
  asm("v_exp_f32 %0, %1" : "=v"(r) : "v"(x));
  return r;
}

// ---------------- fused fp32 -> bf16 conversion (x | Wqkv | Wout) ----------------
__global__ __launch_bounds__(256) void cvt_all(const float* __restrict__ x,
                                               const float* __restrict__ wqkv,
                                               const float* __restrict__ wout,
                                               u16* __restrict__ xb,
                                               u16* __restrict__ wqkvb,
                                               u16* __restrict__ woutb) {
  long i = ((long)blockIdx.x * 256 + threadIdx.x) * 8;
  const float* s;
  u16* d;
  long off;
  if (i < 8388608) {
    s = x; d = xb; off = i;
  } else if (i < 20971520) {
    s = wqkv; d = wqkvb; off = i - 8388608;
  } else {
    s = wout; d = woutb; off = i - 20971520;
  }
  f32x4 a = *(const f32x4*)(s + off);
  f32x4 b = *(const f32x4*)(s + off + 4);
  short8 o;
#pragma unroll
  for (int j = 0; j < 4; j++) {
    o[j] = (short)f2bf(a[j]);
    o[j + 4] = (short)f2bf(b[j]);
  }
  *(short8*)(d + off) = o;
}

// ---------------- m97-style BT GEMM: C = A(MxK) * B(NxK)^T ----------------
// Epilogue goes through a padded f32 LDS panel (4 rounds of 32 rows) so
// global stores are wide & coalesced.
// EPI=0: q (scaled by 1/sqrt(128)*log2e) & k head-major [B,H,T,128] with
//        RoPE fused for heads<8; v transposed per head [B,H,128,T].
// EPI=1: fp32 row-major MxN via dwordx4.
template <int EPI>
__global__ __launch_bounds__(256) void gemm_bt(const u16* __restrict__ A,
                                               const u16* __restrict__ B,
                                               int K, void* __restrict__ Cv, int N,
                                               const float* __restrict__ cosT,
                                               const float* __restrict__ sinT) {
  __shared__ __align__(16) u16 SMEM[8448];  // staging: As|Bs (16 KB); epilogue: f32[32][132]
  u16* As = SMEM;
  u16* Bs = SMEM + 4096;
  const int m0 = blockIdx.y * 128, n0 = blockIdx.x * 128;
  const int t = threadIdx.x, w = t >> 6, lane = t & 63;
  const int quad = lane >> 4, l15 = lane & 15;
  const int rb = (w >> 1) * 64, cb = (w & 1) * 64;
  f32x4 acc[4][4] = {};
  const u16* ag = A + (size_t)(m0 + w * 16 + (lane >> 2)) * K + (lane & 3) * 8;
  const u16* bg = B + (size_t)(n0 + w * 16 + (lane >> 2)) * K + (lane & 3) * 8;
  u16* al = As + w * 512 + lane * 8;  // lane-contiguous: base + lane*16B
  u16* bl = Bs + w * 512 + lane * 8;
  const size_t rowskip = (size_t)64 * K;
  for (int k0 = 0; k0 < K; k0 += 32) {
    __syncthreads();
    gld16(ag, al);
    gld16(ag + rowskip, al + 2048);
    gld16(bg, bl);
    gld16(bg + rowskip, bl + 2048);
    ag += 32;
    bg += 32;
    __syncthreads();
    short8 af[4], bfr[4];
#pragma unroll
    for (int mf = 0; mf < 4; mf++)
      af[mf] = *(const short8*)&As[(rb + mf * 16 + l15) * 32 + quad * 8];
#pragma unroll
    for (int nf = 0; nf < 4; nf++)
      bfr[nf] = *(const short8*)&Bs[(cb + nf * 16 + l15) * 32 + quad * 8];
#pragma unroll
    for (int mf = 0; mf < 4; mf++)
#pragma unroll
      for (int nf = 0; nf < 4; nf++)
        acc[mf][nf] = mfma16(af[mf], bfr[nf], acc[mf][nf]);
  }

  // ---- epilogue: 4 rounds (one per mf), 32 rows x 128 cols each ----
  float* Es = (float*)SMEM;  // [32][132] f32, pitch 132 -> 2-way banks (free)
  const int tt0m = m0 & 2047;
  const int bb = m0 >> 11;
  const int lr0 = (w >> 1) * 16 + quad * 4;
#pragma unroll
  for (int mf = 0; mf < 4; mf++) {
    __syncthreads();  // previous round's reads done
#pragma unroll
    for (int nf = 0; nf < 4; nf++) {
      const int col = cb + nf * 16 + l15;
#pragma unroll
      for (int rg = 0; rg < 4; rg++) Es[(lr0 + rg) * 132 + col] = acc[mf][nf][rg];
    }
    __syncthreads();  // panel visible
    if (EPI == 1) {
      float* C = (float*)Cv;
#pragma unroll
      for (int it = 0; it < 4; it++) {
        int idx = it * 256 + t;
        int row = idx >> 5, ch = idx & 31;
        int ri = (row < 16) ? (mf * 16 + row) : (64 + mf * 16 + row - 16);
        f32x4 vv = *(const f32x4*)&Es[row * 132 + ch * 4];
        *(f32x4*)&C[(size_t)(m0 + ri) * N + n0 + ch * 4] = vv;
      }
    } else {
      const int which = n0 >> 11;             // 0=q 1=k 2=v (block-uniform)
      const int hh = (n0 & 2047) >> 7;        // head (block-uniform)
      u16* q3 = (u16*)Cv;
      if (which == 2) {
        // vT[bh][di][t]: column reads from Es, 16B stores along t
        u16* vbase = q3 + 16777216 + ((size_t)(bb * 16 + hh) * 128) * 2048;
#pragma unroll
        for (int it = 0; it < 2; it++) {
          int idx = it * 256 + t;
          int di = idx & 127, rc = idx >> 7;  // rc in 0..3 (8-row chunk)
          int r0 = rc * 8;
          int tb = tt0m + ((r0 < 16) ? (mf * 16 + r0) : (64 + mf * 16 + r0 - 16));
          short8 o;
#pragma unroll
          for (int j = 0; j < 8; j++) o[j] = (short)f2bf(Es[(r0 + j) * 132 + di]);
          *(short8*)(vbase + (size_t)di * 2048 + tb) = o;
        }
      } else {
        const float sc = (which == 0) ? 0.1275174f : 1.0f;  // 1/sqrt(128)*log2(e)
        const bool doRope = (hh < 8);
        u16* base = q3 + (size_t)which * 8388608 + ((size_t)(bb * 16 + hh) * 2048) * 128;
#pragma unroll
        for (int it = 0; it < 4; it++) {
          int idx = it * 256 + t;
          int row = idx >> 5, ch = idx & 31;
          int ri = (row < 16) ? (mf * 16 + row) : (64 + mf * 16 + row - 16);
          int tt = tt0m + ri;
          f32x4 vv = *(const f32x4*)&Es[row * 132 + ch * 4];
          vv *= sc;
          if (doRope) {
            float2 cc = *(const float2*)&cosT[(size_t)tt * 64 + ch * 2];
            float2 ss = *(const float2*)&sinT[(size_t)tt * 64 + ch * 2];
            float r0 = vv[0] * cc.x - vv[1] * ss.x;
            float i0 = vv[0] * ss.x + vv[1] * cc.x;
            float r1 = vv[2] * cc.y - vv[3] * ss.y;
            float i1 = vv[2] * ss.y + vv[3] * cc.y;
            vv[0] = r0; vv[1] = i0; vv[2] = r1; vv[3] = i1;
          }
          s16x4 o;
#pragma unroll
          for (int j = 0; j < 4; j++) o[j] = (short)f2bf(vv[j]);
          *(s16x4*)(base + (size_t)tt * 128 + ch * 4) = o;
        }
      }
    }
  }
}

// ---------------- flash attention, S^T orientation ----------------
// Q-tile 128 (4 waves x 32 q), K-tile 64. In-register online softmax
// (in-lane + shfl_xor 16/32). P^T in C-layout feeds 16x16x16 PV MFMA
// directly (B-frag == lane's own values) -> no P LDS round trip.
// 2 barriers per tile. Scores already scaled by 1/sqrt(128)*log2e -> exp2.
__global__ __launch_bounds__(256, 2) void attn_k(const u16* __restrict__ qh,
                                                 const u16* __restrict__ kh,
                                                 const u16* __restrict__ vTh,
                                                 u16* __restrict__ attno) {
  __shared__ __align__(16) u16 Ks[8192];  // 64 keys x 128 d, XOR-swizzled 16B chunks
  __shared__ __align__(16) u16 Vt[8192];  // 128 d x 64 keys, XOR-swizzled 16B chunks
  // blocks i and i+256 get complementary qt -> constant paired work (34 tiles)
  const int i = blockIdx.x;
  const int jj = i & 255, half = i >> 8;
  const int bh = jj >> 3, t8 = jj & 7;
  const int qt = half ? (15 - t8) : t8;
  const int q0 = qt * 128;
  const int t = threadIdx.x, w = t >> 6, lane = t & 63;
  const int quad = lane >> 4, l15 = lane & 15;
  const size_t bhoff = (size_t)bh * 262144;

  // Q B-frags in registers: Q[q=wq0+qq*16+l15][d=ks*32+quad*8+j]
  short8 qb[2][4];
  {
    const u16* qp = qh + bhoff + (size_t)(q0 + w * 32 + l15) * 128 + quad * 8;
#pragma unroll
    for (int qq = 0; qq < 2; qq++)
#pragma unroll
      for (int ks = 0; ks < 4; ks++)
        qb[qq][ks] = *(const short8*)(qp + qq * 2048 + ks * 32);
  }
  f32x4 of[2][8] = {};  // O^T[d=df*16+quad*4+rg][q=wq0+qq*16+l15]
  float mst[2] = {-1e30f, -1e30f}, lst[2] = {0.f, 0.f};
  const int nkt = 2 * qt + 2;
  const int wq0 = q0 + w * 32;

  for (int kt = 0; kt < nkt; kt++) {
    const int k0 = kt * 64;
    __syncthreads();  // all waves done reading previous K/V
    {
#pragma unroll
      for (int it = 0; it < 4; it++) {  // K: 64 rows x 16 chunks
        int L = it * 256 + t;
        int key = L >> 4, c = L & 15;
        gld16(kh + bhoff + (size_t)(k0 + key) * 128 + ((c ^ (key & 15)) * 8),
              Ks + (size_t)L * 8);
      }
#pragma unroll
      for (int it = 0; it < 4; it++) {  // V^T: 128 rows x 8 chunks
        int L = it * 256 + t;
        int d = L >> 3, c = L & 7;
        gld16(vTh + bhoff + (size_t)d * 2048 + k0 + ((c ^ (d & 7)) * 8),
              Vt + (size_t)L * 8);
      }
    }
    __syncthreads();  // staging visible
    if (k0 <= wq0 + 31) {  // wave has at least one unmasked key
      // S^T = K * Q^T : C[key=kk*16+quad*4+rg][q=wq0+qq*16+l15]
      f32x4 sacc[2][4];
#pragma unroll
      for (int qq = 0; qq < 2; qq++)
#pragma unroll
        for (int kk = 0; kk < 4; kk++) sacc[qq][kk] = (f32x4){0.f, 0.f, 0.f, 0.f};
#pragma unroll
      for (int kk = 0; kk < 4; kk++) {
        short8 kf[4];
#pragma unroll
        for (int ks = 0; ks < 4; ks++)
          kf[ks] = *(const short8*)&Ks[(kk * 16 + l15) * 128 + ((ks * 4 + quad) ^ l15) * 8];
#pragma unroll
        for (int qq = 0; qq < 2; qq++)
#pragma unroll
          for (int ks = 0; ks < 4; ks++)
            sacc[qq][kk] = mfma16(kf[ks], qb[qq][ks], sacc[qq][kk]);
      }
      const bool needmask = (k0 + 63 > wq0);
      s16x4 pf[2][4];
      float alpha[2];
#pragma unroll
      for (int qq = 0; qq < 2; qq++) {
        const int qg = wq0 + qq * 16 + l15;
        if (needmask) {
#pragma unroll
          for (int kk = 0; kk < 4; kk++)
#pragma unroll
            for (int rg = 0; rg < 4; rg++)
              if (k0 + kk * 16 + quad * 4 + rg > qg) sacc[qq][kk][rg] = -1e30f;
        }
        float pm = -1e30f;
#pragma unroll
        for (int kk = 0; kk < 4; kk++)
#pragma unroll
          for (int rg = 0; rg < 4; rg++) pm = fmaxf(pm, sacc[qq][kk][rg]);
        pm = fmaxf(pm, __shfl_xor(pm, 16));
        pm = fmaxf(pm, __shfl_xor(pm, 32));
        float mnew = fmaxf(mst[qq], pm);
        alpha[qq] = exp2a(mst[qq] - mnew);
        mst[qq] = mnew;
        float ps = 0.f;
#pragma unroll
        for (int kk = 0; kk < 4; kk++) {
          float e0 = exp2a(sacc[qq][kk][0] - mnew);
          float e1 = exp2a(sacc[qq][kk][1] - mnew);
          float e2 = exp2a(sacc[qq][kk][2] - mnew);
          float e3 = exp2a(sacc[qq][kk][3] - mnew);
          ps += (e0 + e1) + (e2 + e3);
          pf[qq][kk][0] = (short)f2bf(e0);
          pf[qq][kk][1] = (short)f2bf(e1);
          pf[qq][kk][2] = (short)f2bf(e2);
          pf[qq][kk][3] = (short)f2bf(e3);
        }
        ps += __shfl_xor(ps, 16);
        ps += __shfl_xor(ps, 32);
        lst[qq] = lst[qq] * alpha[qq] + ps;
      }
#pragma unroll
      for (int qq = 0; qq < 2; qq++) {
        if (!__all(alpha[qq] == 1.0f)) {
          float a = alpha[qq];
#pragma unroll
          for (int df = 0; df < 8; df++) of[qq][df] *= a;
        }
      }
      // O^T += V^T * P^T (16x16x16): A from Vt LDS, B = lane's own pf
#pragma unroll
      for (int df = 0; df < 8; df++) {
        s16x4 vf[4];
#pragma unroll
        for (int kk = 0; kk < 4; kk++)
          vf[kk] = *(const s16x4*)&Vt[(df * 16 + l15) * 64 +
                                      ((kk * 2 + (quad >> 1)) ^ (l15 & 7)) * 8 +
                                      (quad & 1) * 4];
#pragma unroll
        for (int qq = 0; qq < 2; qq++)
#pragma unroll
          for (int kk = 0; kk < 4; kk++)
            of[qq][df] = mfma16k16(vf[kk], pf[qq][kk], of[qq][df]);
      }
    }
  }
  // epilogue: O[q][h*128+d], 4 consecutive d per lane -> 8B stores
  const int b = bh >> 4, h = bh & 15;
#pragma unroll
  for (int qq = 0; qq < 2; qq++) {
    float linv = 1.0f / lst[qq];
    const size_t row = (size_t)(b * 2048 + q0 + w * 32 + qq * 16 + l15);
#pragma unroll
    for (int df = 0; df < 8; df++) {
      s16x4 o;
#pragma unroll
      for (int rg = 0; rg < 4; rg++) o[rg] = (short)f2bf(of[qq][df][rg] * linv);
      *(s16x4*)(attno + row * 2048 + h * 128 + df * 16 + quad * 4) = o;
    }
  }
}

extern "C" void kernel_launch(void* const* d_in, const int* in_sizes, int n_in,
                              void* d_out, int out_size, void* d_ws, size_t ws_size,
                              hipStream_t stream) {
  const float* x = (const float*)d_in[0];
  const float* Wqkv = (const float*)d_in[1];
  const float* Wout = (const float*)d_in[2];
  const float* cosT = (const float*)d_in[3];
  const float* sinT = (const float*)d_in[4];
  float* out = (float*)d_out;
  char* ws = (char*)d_ws;
  // workspace (96 MiB), lifetime-based reuse:
  //   [0,        50331648)  qkvh: q | k | vT (vT = per-head transposed v)
  //   [50331648, 58720256)  woutb (persists to gemm2)
  //   [58720256, 75497472)  xb (dead after gemm1)
  //   [75497472,100663296)  wqkvb (dead after gemm1) -> reused as attno
  u16* qkvh = (u16*)(ws + 0);
  u16* woutb = (u16*)(ws + 50331648);
  u16* xb = (u16*)(ws + 58720256);
  u16* wqkvb = (u16*)(ws + 75497472);
  u16* attno = wqkvb;

  cvt_all<<<12288, 256, 0, stream>>>(x, Wqkv, Wout, xb, wqkvb, woutb);
  gemm_bt<0><<<dim3(48, 32), 256, 0, stream>>>(xb, wqkvb, 2048, (void*)qkvh, 0,
                                               cosT, sinT);
  attn_k<<<512, 256, 0, stream>>>(qkvh, qkvh + 8388608, qkvh + 16777216, attno);
  gemm_bt<1><<<dim3(16, 32), 256, 0, stream>>>(attno, woutb, 2048, (void*)out, 2048,
                                               nullptr, nullptr);
}

// Round 6
// 418.983 us; speedup vs baseline: 1.0251x; 1.0251x over previous
//
#include <hip/hip_runtime.h>
#include <stdint.h>

typedef unsigned short u16;
typedef __attribute__((ext_vector_type(8))) short short8;
typedef __attribute__((ext_vector_type(4))) short s16x4;
typedef __attribute__((ext_vector_type(4))) float f32x4;
typedef __attribute__((ext_vector_type(16))) float f32x16;

__device__ __forceinline__ u16 f2bf(float f) {
  uint32_t x = __float_as_uint(f);
  x += 0x7fff + ((x >> 16) & 1);
  return (u16)(x >> 16);
}
__device__ __forceinline__ float bf2f(u16 u) {
  return __uint_as_float(((uint32_t)u) << 16);
}
__device__ __forceinline__ f32x4 mfma16(short8 a, short8 b, f32x4 c) {
  return __builtin_amdgcn_mfma_f32_16x16x32_bf16(a, b, c, 0, 0, 0);
}
__device__ __forceinline__ f32x16 mfma32(short8 a, short8 b, f32x16 c) {
  return __builtin_amdgcn_mfma_f32_32x32x16_bf16(a, b, c, 0, 0, 0);
}
__device__ __forceinline__ f32x4 mfma16k16(s16x4 a, s16x4 b, f32x4 c) {
  return __builtin_amdgcn_mfma_f32_16x16x16bf16_1k(a, b, c, 0, 0, 0);
}
__device__ __forceinline__ void gld16(const u16* g, u16* l) {
  __builtin_amdgcn_global_load_lds(
      (const __attribute__((address_space(1))) unsigned int*)g,
      (__attribute__((address_space(3))) unsigned int*)l, 16, 0, 0);
}
__device__ __forceinline__ float exp2a(float x) {  // raw v_exp_f32 (2^x)
  float r;
  asm("v_exp_f32 %0, %1" : "=v"(r) : "v"(x));
  return r;
}

// ---------------- fused fp32 -> bf16 conversion (x | Wqkv | Wout) ----------------
__global__ __launch_bounds__(256) void cvt_all(const float* __restrict__ x,
                                               const float* __restrict__ wqkv,
                                               const float* __restrict__ wout,
                                               u16* __restrict__ xb,
                                               u16* __restrict__ wqkvb,
                                               u16* __restrict__ woutb) {
  long i = ((long)blockIdx.x * 256 + threadIdx.x) * 8;
  const float* s;
  u16* d;
  long off;
  if (i < 8388608) {
    s = x; d = xb; off = i;
  } else if (i < 20971520) {
    s = wqkv; d = wqkvb; off = i - 8388608;
  } else {
    s = wout; d = woutb; off = i - 20971520;
  }
  f32x4 a = *(const f32x4*)(s + off);
  f32x4 b = *(const f32x4*)(s + off + 4);
  short8 o;
#pragma unroll
  for (int j = 0; j < 4; j++) {
    o[j] = (short)f2bf(a[j]);
    o[j + 4] = (short)f2bf(b[j]);
  }
  *(short8*)(d + off) = o;
}

// ---------------- BT GEMM, 32x32x16 MFMA: C = A(MxK) * B(NxK)^T ----------------
// Wave tile 64x64 as 2x2 MFMA tiles of 32x32. C-layout (m74/m101):
// col=lane&31, row=(reg&3)+8*(reg>>2)+4*(lane>>5).
// EPI=0: q (scaled by 1/sqrt(128)*log2e) & k head-major [B,H,T,128] scatter;
//        v transposed per head [B,H,128,T] (8B stores along t).
// EPI=1: fp32 row-major MxN via LDS bounce + dwordx4 stores.
template <int EPI>
__global__ __launch_bounds__(256) void gemm_bt(const u16* __restrict__ A,
                                               const u16* __restrict__ B,
                                               int K, void* __restrict__ Cv, int N) {
  __shared__ __align__(16) u16 SMEM[8448];  // staging 16KB; EPI=1 epilogue f32[32][132]
  u16* As = SMEM;
  u16* Bs = SMEM + 4096;
  const int m0 = blockIdx.y * 128, n0 = blockIdx.x * 128;
  const int t = threadIdx.x, w = t >> 6, lane = t & 63;
  const int l31 = lane & 31, half = lane >> 5;
  const int rb = (w >> 1) * 64, cb = (w & 1) * 64;
  f32x16 acc[2][2] = {};
  const u16* ag = A + (size_t)(m0 + w * 16 + (lane >> 2)) * K + (lane & 3) * 8;
  const u16* bg = B + (size_t)(n0 + w * 16 + (lane >> 2)) * K + (lane & 3) * 8;
  u16* al = As + w * 512 + lane * 8;  // lane-contiguous: base + lane*16B
  u16* bl = Bs + w * 512 + lane * 8;
  const size_t rowskip = (size_t)64 * K;
  for (int k0 = 0; k0 < K; k0 += 32) {
    __syncthreads();
    gld16(ag, al);
    gld16(ag + rowskip, al + 2048);
    gld16(bg, bl);
    gld16(bg + rowskip, bl + 2048);
    ag += 32;
    bg += 32;
    __syncthreads();
    short8 af[2][2], bfr[2][2];
#pragma unroll
    for (int mi = 0; mi < 2; mi++)
#pragma unroll
      for (int kh = 0; kh < 2; kh++)
        af[mi][kh] = *(const short8*)&As[(rb + mi * 32 + l31) * 32 + kh * 16 + half * 8];
#pragma unroll
    for (int ni = 0; ni < 2; ni++)
#pragma unroll
      for (int kh = 0; kh < 2; kh++)
        bfr[ni][kh] = *(const short8*)&Bs[(cb + ni * 32 + l31) * 32 + kh * 16 + half * 8];
#pragma unroll
    for (int kh = 0; kh < 2; kh++)
#pragma unroll
      for (int mi = 0; mi < 2; mi++)
#pragma unroll
        for (int ni = 0; ni < 2; ni++)
          acc[mi][ni] = mfma32(af[mi][kh], bfr[ni][kh], acc[mi][ni]);
  }

  if (EPI == 0) {
    const int which = n0 >> 11;       // 0=q 1=k 2=v (block-uniform)
    const int hh = (n0 & 2047) >> 7;  // head (block-uniform)
    const int bb = m0 >> 11, tt0 = m0 & 2047;
    u16* q3 = (u16*)Cv;
    if (which == 2) {
      // vT[bh][di][t]: regs 4r..4r+3 are 4 consecutive t -> 8B stores
      u16* vbase = q3 + 16777216 + ((size_t)(bb * 16 + hh) * 128) * 2048;
#pragma unroll
      for (int mi = 0; mi < 2; mi++)
#pragma unroll
        for (int ni = 0; ni < 2; ni++) {
          int di = cb + ni * 32 + l31;
          int trow = tt0 + rb + mi * 32 + half * 4;
#pragma unroll
          for (int rg2 = 0; rg2 < 4; rg2++) {
            s16x4 st;
#pragma unroll
            for (int j = 0; j < 4; j++) st[j] = (short)f2bf(acc[mi][ni][rg2 * 4 + j]);
            *(s16x4*)(vbase + (size_t)di * 2048 + trow + rg2 * 8) = st;
          }
        }
    } else {
      const float sc = (which == 0) ? 0.1275174f : 1.0f;  // 1/sqrt(128)*log2(e)
      u16* base = q3 + (size_t)which * 8388608 + ((size_t)(bb * 16 + hh) * 2048) * 128;
#pragma unroll
      for (int mi = 0; mi < 2; mi++)
#pragma unroll
        for (int ni = 0; ni < 2; ni++) {
          int di = cb + ni * 32 + l31;
          int trow = tt0 + rb + mi * 32 + half * 4;
#pragma unroll
          for (int reg = 0; reg < 16; reg++) {
            int tt = trow + (reg & 3) + 8 * (reg >> 2);
            base[(size_t)tt * 128 + di] = f2bf(acc[mi][ni][reg] * sc);
          }
        }
    }
  } else {
    // LDS bounce: 4 rounds of 32 rows -> dwordx4 coalesced stores
    float* Es = (float*)SMEM;  // [32][132]
    float* C = (float*)Cv;
#pragma unroll
    for (int r = 0; r < 4; r++) {
      __syncthreads();
      if ((w >> 1) == (r >> 1)) {
        const int mi = r & 1;
#pragma unroll
        for (int ni = 0; ni < 2; ni++) {
          int col = cb + ni * 32 + l31;
#pragma unroll
          for (int reg = 0; reg < 16; reg++) {
            int lrow = (reg & 3) + 8 * (reg >> 2) + half * 4;
            Es[lrow * 132 + col] = acc[mi][ni][reg];
          }
        }
      }
      __syncthreads();
#pragma unroll
      for (int it = 0; it < 4; it++) {
        int idx = it * 256 + t;
        int row = idx >> 5, ch = idx & 31;
        f32x4 vv = *(const f32x4*)&Es[row * 132 + ch * 4];
        *(f32x4*)&C[(size_t)(m0 + r * 32 + row) * N + n0 + ch * 4] = vv;
      }
    }
  }
}

// ---------------- RoPE in-place on q,k (heads 0..7 only) ----------------
__global__ __launch_bounds__(256) void rope_k(u16* __restrict__ q, u16* __restrict__ k,
                                              const float* __restrict__ cosT,
                                              const float* __restrict__ sinT) {
  int t = threadIdx.x;
  int row = blockIdx.x * 4 + (t >> 6);  // over (b, h<8, tpos)
  int i = t & 63;
  int b = row >> 14;
  int h = (row >> 11) & 7;
  int tp = row & 2047;
  size_t base = ((size_t)((b * 16 + h) * 2048 + tp)) * 128 + 2 * i;
  float c = cosT[tp * 64 + i], s = sinT[tp * 64 + i];
  {
    uint32_t u = *(uint32_t*)(q + base);
    float x0 = bf2f((u16)(u & 0xffff)), x1 = bf2f((u16)(u >> 16));
    float re = x0 * c - x1 * s, im = x0 * s + x1 * c;
    *(uint32_t*)(q + base) = (uint32_t)f2bf(re) | ((uint32_t)f2bf(im) << 16);
  }
  {
    uint32_t u = *(uint32_t*)(k + base);
    float x0 = bf2f((u16)(u & 0xffff)), x1 = bf2f((u16)(u >> 16));
    float re = x0 * c - x1 * s, im = x0 * s + x1 * c;
    *(uint32_t*)(k + base) = (uint32_t)f2bf(re) | ((uint32_t)f2bf(im) << 16);
  }
}

// ---------------- flash attention, S^T orientation ----------------
// Q-tile 128 (4 waves x 32 q), K-tile 64. In-register online softmax
// (in-lane + shfl_xor 16/32). P^T in C-layout feeds 16x16x16 PV MFMA
// directly (B-frag == lane's own values) -> no P LDS round trip.
// 2 barriers per tile. Scores already scaled by 1/sqrt(128)*log2e -> exp2.
__global__ __launch_bounds__(256, 2) void attn_k(const u16* __restrict__ qh,
                                                 const u16* __restrict__ kh,
                                                 const u16* __restrict__ vTh,
                                                 u16* __restrict__ attno) {
  __shared__ __align__(16) u16 Ks[8192];  // 64 keys x 128 d, XOR-swizzled 16B chunks
  __shared__ __align__(16) u16 Vt[8192];  // 128 d x 64 keys, XOR-swizzled 16B chunks
  // blocks i and i+256 get complementary qt -> constant paired work (34 tiles)
  const int i = blockIdx.x;
  const int jj = i & 255, half = i >> 8;
  const int bh = jj >> 3, t8 = jj & 7;
  const int qt = half ? (15 - t8) : t8;
  const int q0 = qt * 128;
  const int t = threadIdx.x, w = t >> 6, lane = t & 63;
  const int quad = lane >> 4, l15 = lane & 15;
  const size_t bhoff = (size_t)bh * 262144;

  // Q B-frags in registers: Q[q=wq0+qq*16+l15][d=ks*32+quad*8+j]
  short8 qb[2][4];
  {
    const u16* qp = qh + bhoff + (size_t)(q0 + w * 32 + l15) * 128 + quad * 8;
#pragma unroll
    for (int qq = 0; qq < 2; qq++)
#pragma unroll
      for (int ks = 0; ks < 4; ks++)
        qb[qq][ks] = *(const short8*)(qp + qq * 2048 + ks * 32);
  }
  f32x4 of[2][8] = {};  // O^T[d=df*16+quad*4+rg][q=wq0+qq*16+l15]
  float mst[2] = {-1e30f, -1e30f}, lst[2] = {0.f, 0.f};
  const int nkt = 2 * qt + 2;
  const int wq0 = q0 + w * 32;

  for (int kt = 0; kt < nkt; kt++) {
    const int k0 = kt * 64;
    __syncthreads();  // all waves done reading previous K/V
    {
#pragma unroll
      for (int it = 0; it < 4; it++) {  // K: 64 rows x 16 chunks
        int L = it * 256 + t;
        int key = L >> 4, c = L & 15;
        gld16(kh + bhoff + (size_t)(k0 + key) * 128 + ((c ^ (key & 15)) * 8),
              Ks + (size_t)L * 8);
      }
#pragma unroll
      for (int it = 0; it < 4; it++) {  // V^T: 128 rows x 8 chunks
        int L = it * 256 + t;
        int d = L >> 3, c = L & 7;
        gld16(vTh + bhoff + (size_t)d * 2048 + k0 + ((c ^ (d & 7)) * 8),
              Vt + (size_t)L * 8);
      }
    }
    __syncthreads();  // staging visible
    if (k0 <= wq0 + 31) {  // wave has at least one unmasked key
      // S^T = K * Q^T : C[key=kk*16+quad*4+rg][q=wq0+qq*16+l15]
      f32x4 sacc[2][4];
#pragma unroll
      for (int qq = 0; qq < 2; qq++)
#pragma unroll
        for (int kk = 0; kk < 4; kk++) sacc[qq][kk] = (f32x4){0.f, 0.f, 0.f, 0.f};
#pragma unroll
      for (int kk = 0; kk < 4; kk++) {
        short8 kf[4];
#pragma unroll
        for (int ks = 0; ks < 4; ks++)
          kf[ks] = *(const short8*)&Ks[(kk * 16 + l15) * 128 + ((ks * 4 + quad) ^ l15) * 8];
#pragma unroll
        for (int qq = 0; qq < 2; qq++)
#pragma unroll
          for (int ks = 0; ks < 4; ks++)
            sacc[qq][kk] = mfma16(kf[ks], qb[qq][ks], sacc[qq][kk]);
      }
      const bool needmask = (k0 + 63 > wq0);
      s16x4 pf[2][4];
      float alpha[2];
#pragma unroll
      for (int qq = 0; qq < 2; qq++) {
        const int qg = wq0 + qq * 16 + l15;
        if (needmask) {
#pragma unroll
          for (int kk = 0; kk < 4; kk++)
#pragma unroll
            for (int rg = 0; rg < 4; rg++)
              if (k0 + kk * 16 + quad * 4 + rg > qg) sacc[qq][kk][rg] = -1e30f;
        }
        float pm = -1e30f;
#pragma unroll
        for (int kk = 0; kk < 4; kk++)
#pragma unroll
          for (int rg = 0; rg < 4; rg++) pm = fmaxf(pm, sacc[qq][kk][rg]);
        pm = fmaxf(pm, __shfl_xor(pm, 16));
        pm = fmaxf(pm, __shfl_xor(pm, 32));
        float mnew = fmaxf(mst[qq], pm);
        alpha[qq] = exp2a(mst[qq] - mnew);
        mst[qq] = mnew;
        float ps = 0.f;
#pragma unroll
        for (int kk = 0; kk < 4; kk++) {
          float e0 = exp2a(sacc[qq][kk][0] - mnew);
          float e1 = exp2a(sacc[qq][kk][1] - mnew);
          float e2 = exp2a(sacc[qq][kk][2] - mnew);
          float e3 = exp2a(sacc[qq][kk][3] - mnew);
          ps += (e0 + e1) + (e2 + e3);
          pf[qq][kk][0] = (short)f2bf(e0);
          pf[qq][kk][1] = (short)f2bf(e1);
          pf[qq][kk][2] = (short)f2bf(e2);
          pf[qq][kk][3] = (short)f2bf(e3);
        }
        ps += __shfl_xor(ps, 16);
        ps += __shfl_xor(ps, 32);
        lst[qq] = lst[qq] * alpha[qq] + ps;
      }
#pragma unroll
      for (int qq = 0; qq < 2; qq++) {
        if (!__all(alpha[qq] == 1.0f)) {
          float a = alpha[qq];
#pragma unroll
          for (int df = 0; df < 8; df++) of[qq][df] *= a;
        }
      }
      // O^T += V^T * P^T (16x16x16): A from Vt LDS, B = lane's own pf
#pragma unroll
      for (int df = 0; df < 8; df++) {
        s16x4 vf[4];
#pragma unroll
        for (int kk = 0; kk < 4; kk++)
          vf[kk] = *(const s16x4*)&Vt[(df * 16 + l15) * 64 +
                                      ((kk * 2 + (quad >> 1)) ^ (l15 & 7)) * 8 +
                                      (quad & 1) * 4];
#pragma unroll
        for (int qq = 0; qq < 2; qq++)
#pragma unroll
          for (int kk = 0; kk < 4; kk++)
            of[qq][df] = mfma16k16(vf[kk], pf[qq][kk], of[qq][df]);
      }
    }
  }
  // epilogue: O[q][h*128+d], 4 consecutive d per lane -> 8B stores
  const int b = bh >> 4, h = bh & 15;
#pragma unroll
  for (int qq = 0; qq < 2; qq++) {
    float linv = 1.0f / lst[qq];
    const size_t row = (size_t)(b * 2048 + q0 + w * 32 + qq * 16 + l15);
#pragma unroll
    for (int df = 0; df < 8; df++) {
      s16x4 o;
#pragma unroll
      for (int rg = 0; rg < 4; rg++) o[rg] = (short)f2bf(of[qq][df][rg] * linv);
      *(s16x4*)(attno + row * 2048 + h * 128 + df * 16 + quad * 4) = o;
    }
  }
}

extern "C" void kernel_launch(void* const* d_in, const int* in_sizes, int n_in,
                              void* d_out, int out_size, void* d_ws, size_t ws_size,
                              hipStream_t stream) {
  const float* x = (const float*)d_in[0];
  const float* Wqkv = (const float*)d_in[1];
  const float* Wout = (const float*)d_in[2];
  const float* cosT = (const float*)d_in[3];
  const float* sinT = (const float*)d_in[4];
  float* out = (float*)d_out;
  char* ws = (char*)d_ws;
  // workspace (96 MiB), lifetime-based reuse:
  //   [0,        50331648)  qkvh: q | k | vT (vT = per-head transposed v)
  //   [50331648, 58720256)  woutb (persists to gemm2)
  //   [58720256, 75497472)  xb (dead after gemm1)
  //   [75497472,100663296)  wqkvb (dead after gemm1) -> reused as attno
  u16* qkvh = (u16*)(ws + 0);
  u16* woutb = (u16*)(ws + 50331648);
  u16* xb = (u16*)(ws + 58720256);
  u16* wqkvb = (u16*)(ws + 75497472);
  u16* attno = wqkvb;

  cvt_all<<<12288, 256, 0, stream>>>(x, Wqkv, Wout, xb, wqkvb, woutb);
  gemm_bt<0><<<dim3(48, 32), 256, 0, stream>>>(xb, wqkvb, 2048, (void*)qkvh, 0);
  rope_k<<<8192, 256, 0, stream>>>(qkvh, qkvh + 8388608, cosT, sinT);
  attn_k<<<512, 256, 0, stream>>>(qkvh, qkvh + 8388608, qkvh + 16777216, attno);
  gemm_bt<1><<<dim3(16, 32), 256, 0, stream>>>(attno, woutb, 2048, (void*)out, 2048);
}

// Round 7
// 407.034 us; speedup vs baseline: 1.0552x; 1.0294x over previous
//
#include <hip/hip_runtime.h>
#include <stdint.h>

typedef unsigned short u16;
typedef __attribute__((ext_vector_type(8))) short short8;
typedef __attribute__((ext_vector_type(4))) short s16x4;
typedef __attribute__((ext_vector_type(4))) float f32x4;
typedef __attribute__((ext_vector_type(16))) float f32x16;

__device__ __forceinline__ u16 f2bf(float f) {
  uint32_t x = __float_as_uint(f);
  x += 0x7fff + ((x >> 16) & 1);
  return (u16)(x >> 16);
}
__device__ __forceinline__ float bf2f(u16 u) {
  return __uint_as_float(((uint32_t)u) << 16);
}
__device__ __forceinline__ f32x4 mfma16(short8 a, short8 b, f32x4 c) {
  return __builtin_amdgcn_mfma_f32_16x16x32_bf16(a, b, c, 0, 0, 0);
}
__device__ __forceinline__ f32x16 mfma32(short8 a, short8 b, f32x16 c) {
  return __builtin_amdgcn_mfma_f32_32x32x16_bf16(a, b, c, 0, 0, 0);
}
__device__ __forceinline__ f32x4 mfma16k16(s16x4 a, s16x4 b, f32x4 c) {
  return __builtin_amdgcn_mfma_f32_16x16x16bf16_1k(a, b, c, 0, 0, 0);
}
__device__ __forceinline__ void gld16(const u16* g, u16* l) {
  __builtin_amdgcn_global_load_lds(
      (const __attribute__((address_space(1))) unsigned int*)g,
      (__attribute__((address_space(3))) unsigned int*)l, 16, 0, 0);
}
__device__ __forceinline__ float exp2a(float x) {  // raw v_exp_f32 (2^x)
  float r;
  asm("v_exp_f32 %0, %1" : "=v"(r) : "v"(x));
  return r;
}

// ---------------- fused fp32 -> bf16 conversion (x | Wqkv | Wout) ----------------
__global__ __launch_bounds__(256) void cvt_all(const float* __restrict__ x,
                                               const float* __restrict__ wqkv,
                                               const float* __restrict__ wout,
                                               u16* __restrict__ xb,
                                               u16* __restrict__ wqkvb,
                                               u16* __restrict__ woutb) {
  long i = ((long)blockIdx.x * 256 + threadIdx.x) * 8;
  const float* s;
  u16* d;
  long off;
  if (i < 8388608) {
    s = x; d = xb; off = i;
  } else if (i < 20971520) {
    s = wqkv; d = wqkvb; off = i - 8388608;
  } else {
    s = wout; d = woutb; off = i - 20971520;
  }
  f32x4 a = *(const f32x4*)(s + off);
  f32x4 b = *(const f32x4*)(s + off + 4);
  short8 o;
#pragma unroll
  for (int j = 0; j < 4; j++) {
    o[j] = (short)f2bf(a[j]);
    o[j + 4] = (short)f2bf(b[j]);
  }
  *(short8*)(d + off) = o;
}

// ---------------- BT GEMM, 32x32x16 MFMA: C = A(MxK) * B(NxK)^T ----------------
// LDS K-chunk swizzle: the 16B chunk stored at row r, position p holds global
// chunk c = (p - (r>>1)) & 3. Staging permutes the global source column per
// lane (LDS dest stays lane-contiguous for global_load_lds); fragment reads
// use p = (c + (r>>1)) & 3 -> all 8 bank positions covered per 8 rows = b128
// conflict floor.
// EPI=0: q (scaled by 1/sqrt(128)*log2e) & k head-major [B,H,T,128] scatter;
//        v transposed per head [B,H,128,T] (8B stores along t).
// EPI=1: fp32 row-major MxN via LDS bounce + dwordx4 stores.
template <int EPI>
__global__ __launch_bounds__(256) void gemm_bt(const u16* __restrict__ A,
                                               const u16* __restrict__ B,
                                               int K, void* __restrict__ Cv, int N) {
  __shared__ __align__(16) u16 SMEM[8448];  // staging 16KB; EPI=1 epilogue f32[32][132]
  u16* As = SMEM;
  u16* Bs = SMEM + 4096;
  const int m0 = blockIdx.y * 128, n0 = blockIdx.x * 128;
  const int t = threadIdx.x, w = t >> 6, lane = t & 63;
  const int l31 = lane & 31, half = lane >> 5;
  const int rb = (w >> 1) * 64, cb = (w & 1) * 64;
  f32x16 acc[2][2] = {};
  const int rowS = w * 16 + (lane >> 2);                // staged row (0..63, +64 second)
  const int cS = ((lane & 3) - (rowS >> 1)) & 3;        // swizzled source chunk
  const u16* ag = A + (size_t)(m0 + rowS) * K + cS * 8;
  const u16* bg = B + (size_t)(n0 + rowS) * K + cS * 8;
  u16* al = As + w * 512 + lane * 8;  // lane-contiguous: base + lane*16B
  u16* bl = Bs + w * 512 + lane * 8;
  const size_t rowskip = (size_t)64 * K;
  // fragment-read swizzled positions (row>>1 & 3 == l31>>1 & 3 at rb/mi strides)
  const int p0 = ((0 * 2 + half + (l31 >> 1)) & 3) * 8;  // kh=0
  const int p1 = ((1 * 2 + half + (l31 >> 1)) & 3) * 8;  // kh=1
  for (int k0 = 0; k0 < K; k0 += 32) {
    __syncthreads();
    gld16(ag, al);
    gld16(ag + rowskip, al + 2048);
    gld16(bg, bl);
    gld16(bg + rowskip, bl + 2048);
    ag += 32;
    bg += 32;
    __syncthreads();
    short8 af[2][2], bfr[2][2];
#pragma unroll
    for (int mi = 0; mi < 2; mi++) {
      af[mi][0] = *(const short8*)&As[(rb + mi * 32 + l31) * 32 + p0];
      af[mi][1] = *(const short8*)&As[(rb + mi * 32 + l31) * 32 + p1];
    }
#pragma unroll
    for (int ni = 0; ni < 2; ni++) {
      bfr[ni][0] = *(const short8*)&Bs[(cb + ni * 32 + l31) * 32 + p0];
      bfr[ni][1] = *(const short8*)&Bs[(cb + ni * 32 + l31) * 32 + p1];
    }
#pragma unroll
    for (int kh = 0; kh < 2; kh++)
#pragma unroll
      for (int mi = 0; mi < 2; mi++)
#pragma unroll
        for (int ni = 0; ni < 2; ni++)
          acc[mi][ni] = mfma32(af[mi][kh], bfr[ni][kh], acc[mi][ni]);
  }

  if (EPI == 0) {
    const int which = n0 >> 11;       // 0=q 1=k 2=v (block-uniform)
    const int hh = (n0 & 2047) >> 7;  // head (block-uniform)
    const int bb = m0 >> 11, tt0 = m0 & 2047;
    u16* q3 = (u16*)Cv;
    if (which == 2) {
      // vT[bh][di][t]: regs 4r..4r+3 are 4 consecutive t -> 8B stores
      u16* vbase = q3 + 16777216 + ((size_t)(bb * 16 + hh) * 128) * 2048;
#pragma unroll
      for (int mi = 0; mi < 2; mi++)
#pragma unroll
        for (int ni = 0; ni < 2; ni++) {
          int di = cb + ni * 32 + l31;
          int trow = tt0 + rb + mi * 32 + half * 4;
#pragma unroll
          for (int rg2 = 0; rg2 < 4; rg2++) {
            s16x4 st;
#pragma unroll
            for (int j = 0; j < 4; j++) st[j] = (short)f2bf(acc[mi][ni][rg2 * 4 + j]);
            *(s16x4*)(vbase + (size_t)di * 2048 + trow + rg2 * 8) = st;
          }
        }
    } else {
      const float sc = (which == 0) ? 0.1275174f : 1.0f;  // 1/sqrt(128)*log2(e)
      u16* base = q3 + (size_t)which * 8388608 + ((size_t)(bb * 16 + hh) * 2048) * 128;
#pragma unroll
      for (int mi = 0; mi < 2; mi++)
#pragma unroll
        for (int ni = 0; ni < 2; ni++) {
          int di = cb + ni * 32 + l31;
          int trow = tt0 + rb + mi * 32 + half * 4;
#pragma unroll
          for (int reg = 0; reg < 16; reg++) {
            int tt = trow + (reg & 3) + 8 * (reg >> 2);
            base[(size_t)tt * 128 + di] = f2bf(acc[mi][ni][reg] * sc);
          }
        }
    }
  } else {
    // LDS bounce: 4 rounds of 32 rows -> dwordx4 coalesced stores
    float* Es = (float*)SMEM;  // [32][132]
    float* C = (float*)Cv;
#pragma unroll
    for (int r = 0; r < 4; r++) {
      __syncthreads();
      if ((w >> 1) == (r >> 1)) {
        const int mi = r & 1;
#pragma unroll
        for (int ni = 0; ni < 2; ni++) {
          int col = cb + ni * 32 + l31;
#pragma unroll
          for (int reg = 0; reg < 16; reg++) {
            int lrow = (reg & 3) + 8 * (reg >> 2) + half * 4;
            Es[lrow * 132 + col] = acc[mi][ni][reg];
          }
        }
      }
      __syncthreads();
#pragma unroll
      for (int it = 0; it < 4; it++) {
        int idx = it * 256 + t;
        int row = idx >> 5, ch = idx & 31;
        f32x4 vv = *(const f32x4*)&Es[row * 132 + ch * 4];
        *(f32x4*)&C[(size_t)(m0 + r * 32 + row) * N + n0 + ch * 4] = vv;
      }
    }
  }
}

// ---------------- RoPE in-place on q,k (heads 0..7 only) ----------------
__global__ __launch_bounds__(256) void rope_k(u16* __restrict__ q, u16* __restrict__ k,
                                              const float* __restrict__ cosT,
                                              const float* __restrict__ sinT) {
  int t = threadIdx.x;
  int row = blockIdx.x * 4 + (t >> 6);  // over (b, h<8, tpos)
  int i = t & 63;
  int b = row >> 14;
  int h = (row >> 11) & 7;
  int tp = row & 2047;
  size_t base = ((size_t)((b * 16 + h) * 2048 + tp)) * 128 + 2 * i;
  float c = cosT[tp * 64 + i], s = sinT[tp * 64 + i];
  {
    uint32_t u = *(uint32_t*)(q + base);
    float x0 = bf2f((u16)(u & 0xffff)), x1 = bf2f((u16)(u >> 16));
    float re = x0 * c - x1 * s, im = x0 * s + x1 * c;
    *(uint32_t*)(q + base) = (uint32_t)f2bf(re) | ((uint32_t)f2bf(im) << 16);
  }
  {
    uint32_t u = *(uint32_t*)(k + base);
    float x0 = bf2f((u16)(u & 0xffff)), x1 = bf2f((u16)(u >> 16));
    float re = x0 * c - x1 * s, im = x0 * s + x1 * c;
    *(uint32_t*)(k + base) = (uint32_t)f2bf(re) | ((uint32_t)f2bf(im) << 16);
  }
}

// ---------------- flash attention, S^T orientation ----------------
// Q-tile 128 (4 waves x 32 q), K-tile 64. In-register online softmax
// (in-lane + shfl_xor 16/32). P^T in C-layout feeds 16x16x16 PV MFMA
// directly (B-frag == lane's own values) -> no P LDS round trip.
// 2 barriers per tile. Scores already scaled by 1/sqrt(128)*log2e -> exp2.
__global__ __launch_bounds__(256, 2) void attn_k(const u16* __restrict__ qh,
                                                 const u16* __restrict__ kh,
                                                 const u16* __restrict__ vTh,
                                                 u16* __restrict__ attno) {
  __shared__ __align__(16) u16 Ks[8192];  // 64 keys x 128 d, XOR-swizzled 16B chunks
  __shared__ __align__(16) u16 Vt[8192];  // 128 d x 64 keys, XOR-swizzled 16B chunks
  // blocks i and i+256 get complementary qt -> constant paired work (34 tiles)
  const int i = blockIdx.x;
  const int jj = i & 255, half = i >> 8;
  const int bh = jj >> 3, t8 = jj & 7;
  const int qt = half ? (15 - t8) : t8;
  const int q0 = qt * 128;
  const int t = threadIdx.x, w = t >> 6, lane = t & 63;
  const int quad = lane >> 4, l15 = lane & 15;
  const size_t bhoff = (size_t)bh * 262144;

  // Q B-frags in registers: Q[q=wq0+qq*16+l15][d=ks*32+quad*8+j]
  short8 qb[2][4];
  {
    const u16* qp = qh + bhoff + (size_t)(q0 + w * 32 + l15) * 128 + quad * 8;
#pragma unroll
    for (int qq = 0; qq < 2; qq++)
#pragma unroll
      for (int ks = 0; ks < 4; ks++)
        qb[qq][ks] = *(const short8*)(qp + qq * 2048 + ks * 32);
  }
  f32x4 of[2][8] = {};  // O^T[d=df*16+quad*4+rg][q=wq0+qq*16+l15]
  float mst[2] = {-1e30f, -1e30f}, lst[2] = {0.f, 0.f};
  const int nkt = 2 * qt + 2;
  const int wq0 = q0 + w * 32;

  for (int kt = 0; kt < nkt; kt++) {
    const int k0 = kt * 64;
    __syncthreads();  // all waves done reading previous K/V
    {
#pragma unroll
      for (int it = 0; it < 4; it++) {  // K: 64 rows x 16 chunks
        int L = it * 256 + t;
        int key = L >> 4, c = L & 15;
        gld16(kh + bhoff + (size_t)(k0 + key) * 128 + ((c ^ (key & 15)) * 8),
              Ks + (size_t)L * 8);
      }
#pragma unroll
      for (int it = 0; it < 4; it++) {  // V^T: 128 rows x 8 chunks
        int L = it * 256 + t;
        int d = L >> 3, c = L & 7;
        gld16(vTh + bhoff + (size_t)d * 2048 + k0 + ((c ^ (d & 7)) * 8),
              Vt + (size_t)L * 8);
      }
    }
    __syncthreads();  // staging visible
    if (k0 <= wq0 + 31) {  // wave has at least one unmasked key
      // S^T = K * Q^T : C[key=kk*16+quad*4+rg][q=wq0+qq*16+l15]
      f32x4 sacc[2][4];
#pragma unroll
      for (int qq = 0; qq < 2; qq++)
#pragma unroll
        for (int kk = 0; kk < 4; kk++) sacc[qq][kk] = (f32x4){0.f, 0.f, 0.f, 0.f};
#pragma unroll
      for (int kk = 0; kk < 4; kk++) {
        short8 kf[4];
#pragma unroll
        for (int ks = 0; ks < 4; ks++)
          kf[ks] = *(const short8*)&Ks[(kk * 16 + l15) * 128 + ((ks * 4 + quad) ^ l15) * 8];
#pragma unroll
        for (int qq = 0; qq < 2; qq++)
#pragma unroll
          for (int ks = 0; ks < 4; ks++)
            sacc[qq][kk] = mfma16(kf[ks], qb[qq][ks], sacc[qq][kk]);
      }
      const bool needmask = (k0 + 63 > wq0);
      s16x4 pf[2][4];
      float alpha[2];
#pragma unroll
      for (int qq = 0; qq < 2; qq++) {
        const int qg = wq0 + qq * 16 + l15;
        if (needmask) {
#pragma unroll
          for (int kk = 0; kk < 4; kk++)
#pragma unroll
            for (int rg = 0; rg < 4; rg++)
              if (k0 + kk * 16 + quad * 4 + rg > qg) sacc[qq][kk][rg] = -1e30f;
        }
        float pm = -1e30f;
#pragma unroll
        for (int kk = 0; kk < 4; kk++)
#pragma unroll
          for (int rg = 0; rg < 4; rg++) pm = fmaxf(pm, sacc[qq][kk][rg]);
        pm = fmaxf(pm, __shfl_xor(pm, 16));
        pm = fmaxf(pm, __shfl_xor(pm, 32));
        float mnew = fmaxf(mst[qq], pm);
        alpha[qq] = exp2a(mst[qq] - mnew);
        mst[qq] = mnew;
        float ps = 0.f;
#pragma unroll
        for (int kk = 0; kk < 4; kk++) {
          float e0 = exp2a(sacc[qq][kk][0] - mnew);
          float e1 = exp2a(sacc[qq][kk][1] - mnew);
          float e2 = exp2a(sacc[qq][kk][2] - mnew);
          float e3 = exp2a(sacc[qq][kk][3] - mnew);
          ps += (e0 + e1) + (e2 + e3);
          pf[qq][kk][0] = (short)f2bf(e0);
          pf[qq][kk][1] = (short)f2bf(e1);
          pf[qq][kk][2] = (short)f2bf(e2);
          pf[qq][kk][3] = (short)f2bf(e3);
        }
        ps += __shfl_xor(ps, 16);
        ps += __shfl_xor(ps, 32);
        lst[qq] = lst[qq] * alpha[qq] + ps;
      }
#pragma unroll
      for (int qq = 0; qq < 2; qq++) {
        if (!__all(alpha[qq] == 1.0f)) {
          float a = alpha[qq];
#pragma unroll
          for (int df = 0; df < 8; df++) of[qq][df] *= a;
        }
      }
      // O^T += V^T * P^T (16x16x16): A from Vt LDS, B = lane's own pf
#pragma unroll
      for (int df = 0; df < 8; df++) {
        s16x4 vf[4];
#pragma unroll
        for (int kk = 0; kk < 4; kk++)
          vf[kk] = *(const s16x4*)&Vt[(df * 16 + l15) * 64 +
                                      ((kk * 2 + (quad >> 1)) ^ (l15 & 7)) * 8 +
                                      (quad & 1) * 4];
#pragma unroll
        for (int qq = 0; qq < 2; qq++)
#pragma unroll
          for (int kk = 0; kk < 4; kk++)
            of[qq][df] = mfma16k16(vf[kk], pf[qq][kk], of[qq][df]);
      }
    }
  }
  // epilogue: O[q][h*128+d], 4 consecutive d per lane -> 8B stores
  const int b = bh >> 4, h = bh & 15;
#pragma unroll
  for (int qq = 0; qq < 2; qq++) {
    float linv = 1.0f / lst[qq];
    const size_t row = (size_t)(b * 2048 + q0 + w * 32 + qq * 16 + l15);
#pragma unroll
    for (int df = 0; df < 8; df++) {
      s16x4 o;
#pragma unroll
      for (int rg = 0; rg < 4; rg++) o[rg] = (short)f2bf(of[qq][df][rg] * linv);
      *(s16x4*)(attno + row * 2048 + h * 128 + df * 16 + quad * 4) = o;
    }
  }
}

extern "C" void kernel_launch(void* const* d_in, const int* in_sizes, int n_in,
                              void* d_out, int out_size, void* d_ws, size_t ws_size,
                              hipStream_t stream) {
  const float* x = (const float*)d_in[0];
  const float* Wqkv = (const float*)d_in[1];
  const float* Wout = (const float*)d_in[2];
  const float* cosT = (const float*)d_in[3];
  const float* sinT = (const float*)d_in[4];
  float* out = (float*)d_out;
  char* ws = (char*)d_ws;
  // workspace (96 MiB), lifetime-based reuse:
  //   [0,        50331648)  qkvh: q | k | vT (vT = per-head transposed v)
  //   [50331648, 58720256)  woutb (persists to gemm2)
  //   [58720256, 75497472)  xb (dead after gemm1)
  //   [75497472,100663296)  wqkvb (dead after gemm1) -> reused as attno
  u16* qkvh = (u16*)(ws + 0);
  u16* woutb = (u16*)(ws + 50331648);
  u16* xb = (u16*)(ws + 58720256);
  u16* wqkvb = (u16*)(ws + 75497472);
  u16* attno = wqkvb;

  cvt_all<<<12288, 256, 0, stream>>>(x, Wqkv, Wout, xb, wqkvb, woutb);
  gemm_bt<0><<<dim3(48, 32), 256, 0, stream>>>(xb, wqkvb, 2048, (void*)qkvh, 0);
  rope_k<<<8192, 256, 0, stream>>>(qkvh, qkvh + 8388608, cosT, sinT);
  attn_k<<<512, 256, 0, stream>>>(qkvh, qkvh + 8388608, qkvh + 16777216, attno);
  gemm_bt<1><<<dim3(16, 32), 256, 0, stream>>>(attno, woutb, 2048, (void*)out, 2048);
}